// Round 3
// baseline (363.700 us; speedup 1.0000x reference)
//
#include <hip/hip_runtime.h>

#define B_ 64
#define L_ 1024
#define M_ 256
#define F_ 256

typedef unsigned int u32;

// Async 16B global->LDS DMA (no VGPR round-trip). LDS dest wave-uniform
// base + lane*16; per-lane global src carries the XOR swizzle.
__device__ __forceinline__ void async_cp16(const float* g, float* l) {
    __builtin_amdgcn_global_load_lds(
        (const __attribute__((address_space(1))) u32*)g,
        (__attribute__((address_space(3))) u32*)l,
        16, 0, 0);
}

// One block per l, 512 threads = 8 waves. Wave w owns b-rows w*8..w*8+7
// (wave-uniform -> P loads scalarize to s_load, SGPR operand of v_fmac).
// Lane owns m = lane + 64*j, j=0..3 -> acc[8][4]. Q (only) in LDS,
// double-buffered, staged via global_load_lds with pre-swizzled source.
__launch_bounds__(512, 4)
__global__ void mq_fused_kernel(const float* __restrict__ patch,
                                const float* __restrict__ queue,
                                float* __restrict__ out) {
    const int l    = blockIdx.x;
    const int t    = threadIdx.x;
    const int lane = t & 63;
    const int w    = __builtin_amdgcn_readfirstlane(t >> 6);   // wave id 0..7

    // 2 x 32KB Q buffers = 64KB -> 2 blocks/CU = 16 waves/CU. sidx overlays Ql[0].
    __shared__ float Ql[2][256 * 32];   // [m][f] stride 32, chunk c at c^(m&7)

    // ---- Q staging addresses: 4 chunks/wave, 8 rows x 32 f each ----
    const int lrow = lane >> 3;           // 0..7 row within chunk
    const int lcq  = (lane & 7) ^ lrow;   // pre-swizzled source float4-chunk
    const float* qbase[4];
#pragma unroll
    for (int k = 0; k < 4; ++k)
        qbase[k] = queue + ((size_t)l * M_ + (w * 4 + k) * 8 + lrow) * F_ + lcq * 4;

    // ---- P row pointers (wave-uniform -> SGPR) ----
    const float* prow[8];
#pragma unroll
    for (int i = 0; i < 8; ++i)
        prow[i] = patch + ((size_t)(w * 8 + i) * L_ + l) * F_;

    float acc[8][4];
#pragma unroll
    for (int i = 0; i < 8; ++i)
#pragma unroll
        for (int j = 0; j < 4; ++j) acc[i][j] = 0.f;

    // Prologue: stage K-tile 0 into buffer 0.
#pragma unroll
    for (int k = 0; k < 4; ++k)
        async_cp16(qbase[k], &Ql[0][(w * 4 + k) * 256]);

    for (int ft = 0; ft < 8; ++ft) {
        // Barrier: implicit vmcnt(0) drains this tile's loads (in flight for
        // the whole previous compute phase) and fences buffer reuse.
        __syncthreads();

        if (ft < 7) {
            const int nxt = (ft + 1) & 1;
            const int o   = (ft + 1) * 32;
#pragma unroll
            for (int k = 0; k < 4; ++k)
                async_cp16(qbase[k] + o, &Ql[nxt][(w * 4 + k) * 256]);
        }

        const int cur = ft & 1;
#pragma unroll
        for (int f4 = 0; f4 < 8; ++f4) {
            float4 qr[4];
            const int qc = (f4 ^ (lane & 7)) * 4;   // (lane+64j)&7 == lane&7
#pragma unroll
            for (int j = 0; j < 4; ++j)
                qr[j] = *reinterpret_cast<const float4*>(
                    &Ql[cur][(lane + 64 * j) * 32 + qc]);
#pragma unroll
            for (int i = 0; i < 8; ++i) {
                // wave-uniform global read -> s_load_dwordx4 (scalar pipe)
                const float4 pv = *reinterpret_cast<const float4*>(
                    prow[i] + ft * 32 + f4 * 4);
#pragma unroll
                for (int j = 0; j < 4; ++j) {
                    acc[i][j] += pv.x * qr[j].x;
                    acc[i][j] += pv.y * qr[j].y;
                    acc[i][j] += pv.z * qr[j].z;
                    acc[i][j] += pv.w * qr[j].w;
                }
            }
        }
    }

    // argmax over m per b (numpy first-occurrence). In-thread j ascending =>
    // m ascending, strict '>' keeps first; butterfly prefers lower idx on tie.
    // Final compute used Ql[1]; sidx overlays Ql[0] (idle since the ft=7 barrier).
    int* sidx = (int*)&Ql[0][0];
#pragma unroll
    for (int i = 0; i < 8; ++i) {
        float bv = acc[i][0];
        int   bi = lane;
#pragma unroll
        for (int j = 1; j < 4; ++j) {
            const float cv = acc[i][j];
            const int   ci = lane + 64 * j;
            if (cv > bv) { bv = cv; bi = ci; }
        }
#pragma unroll
        for (int off = 32; off >= 1; off >>= 1) {
            const float ov = __shfl_xor(bv, off);
            const int   oi = __shfl_xor(bi, off);
            if (ov > bv || (ov == bv && oi < bi)) { bv = ov; bi = oi; }
        }
        if (lane == 0) sidx[w * 8 + i] = bi;
    }
    __syncthreads();

    // gather: out[b][l][:] = queue[l][sidx[b]][:]  (queue[l] is L2-hot)
    const int cb = t >> 6;     // 0..7
    const int cc = t & 63;     // float4 index within the 256-float row
#pragma unroll
    for (int b0 = 0; b0 < 64; b0 += 8) {
        const int b  = b0 + cb;
        const int mi = sidx[b];
        const float4 v = *reinterpret_cast<const float4*>(
            &queue[((size_t)l * M_ + mi) * F_ + cc * 4]);
        *reinterpret_cast<float4*>(&out[((size_t)b * L_ + l) * F_ + cc * 4]) = v;
    }
}

extern "C" void kernel_launch(void* const* d_in, const int* in_sizes, int n_in,
                              void* d_out, int out_size, void* d_ws, size_t ws_size,
                              hipStream_t stream) {
    const float* patch = (const float*)d_in[0];
    const float* queue = (const float*)d_in[1];
    float* out = (float*)d_out;
    mq_fused_kernel<<<dim3(L_), dim3(512), 0, stream>>>(patch, queue, out);
}

// Round 4
// 276.671 us; speedup vs baseline: 1.3146x; 1.3146x over previous
//
#include <hip/hip_runtime.h>

#define B_ 64
#define L_ 1024
#define M_ 256
#define F_ 256

typedef unsigned int u32;

// Async 16B global->LDS DMA. LDS dest is wave-uniform base + lane*16;
// the per-lane global src address carries the swizzle (m173 pattern).
__device__ __forceinline__ void async_cp16(const float* g, float* l) {
    __builtin_amdgcn_global_load_lds(
        (const __attribute__((address_space(1))) u32*)g,
        (__attribute__((address_space(3))) u32*)l,
        16, 0, 0);
}

// One block per l, 256 threads, rt 8x8: m = tx+32j (j=0..7), b = ty*8+i.
// K tiled by 16 f. LDS = 2*(Q 16KB + P 4KB) = 40960 B -> 4 blocks/CU,
// exactly matching grid 1024 / 256 CUs. Q source-pre-swizzled for
// conflict-free b128 reads; P linear (reads are 2-way broadcast = free).
__launch_bounds__(256, 4)
__global__ void mq_fused_kernel(const float* __restrict__ patch,
                                const float* __restrict__ queue,
                                float* __restrict__ out) {
    const int l    = blockIdx.x;
    const int t    = threadIdx.x;
    const int tx   = t & 31;
    const int ty   = t >> 5;
    const int lane = t & 63;
    const int w    = t >> 6;          // wave 0..3

    __shared__ __align__(16) float Ql[2][256 * 16];  // [m][slot] 32KB total
    __shared__ __align__(16) float Pl[2][64 * 16];   // [b][slot]  8KB total

    // ---- staging geometry ----
    const int srow  = lane >> 2;      // 0..15: row within a 16-row group
    const int sslot = lane & 3;       // float4 slot within a 64B row

    // Q: wave w stages groups g = k*4 + w (k=0..3), rows g*16 + srow.
    // LDS slot s holds global chunk s ^ swz(row), swz(row) = (row>>1)&3
    // (XOR involution: read of logical chunk c fetches slot c ^ swz(row)).
    const float* qsrc[4];
    int qdst[4];
#pragma unroll
    for (int k = 0; k < 4; ++k) {
        const int g   = k * 4 + w;
        const int row = g * 16 + srow;
        qsrc[k] = queue + ((size_t)l * M_ + row) * F_ + (sslot ^ ((row >> 1) & 3)) * 4;
        qdst[k] = g * 256;            // wave-uniform float offset into Ql[buf]
    }
    // P: wave w stages rows w*16 + srow, linear.
    const int prow = w * 16 + srow;
    const float* psrc = patch + ((size_t)prow * L_ + l) * F_ + sslot * 4;
    const int pdst = w * 256;

    float acc[8][8];
#pragma unroll
    for (int i = 0; i < 8; ++i)
#pragma unroll
        for (int j = 0; j < 8; ++j) acc[i][j] = 0.f;

    // Prologue: stage K-tile 0 into buffer 0.
#pragma unroll
    for (int k = 0; k < 4; ++k) async_cp16(qsrc[k], &Ql[0][qdst[k]]);
    async_cp16(psrc, &Pl[0][pdst]);

    const int qslotx = (tx >> 1) & 3;   // (tx+32j)>>1 &3 == (tx>>1)&3

    for (int ft = 0; ft < 16; ++ft) {
        // Barrier (implicit vmcnt(0) drain): this tile's loads had the whole
        // previous compute phase in flight; also fences buffer reuse.
        __syncthreads();

        if (ft < 15) {
            const int nxt = (ft + 1) & 1;
            const int o   = (ft + 1) * 16;
#pragma unroll
            for (int k = 0; k < 4; ++k)
                async_cp16(qsrc[k] + o, &Ql[nxt][qdst[k]]);
            async_cp16(psrc + o, &Pl[nxt][pdst]);
        }

        const int cur = ft & 1;
#pragma unroll
        for (int f4 = 0; f4 < 4; ++f4) {
            float4 qr[8];
            const int qs = (f4 ^ qslotx) * 4;
#pragma unroll
            for (int j = 0; j < 8; ++j)
                qr[j] = *reinterpret_cast<const float4*>(
                    &Ql[cur][(tx + 32 * j) * 16 + qs]);
#pragma unroll
            for (int i = 0; i < 8; ++i) {
                const float4 pv = *reinterpret_cast<const float4*>(
                    &Pl[cur][(ty * 8 + i) * 16 + f4 * 4]);
#pragma unroll
                for (int j = 0; j < 8; ++j) {
                    acc[i][j] += pv.x * qr[j].x;
                    acc[i][j] += pv.y * qr[j].y;
                    acc[i][j] += pv.z * qr[j].z;
                    acc[i][j] += pv.w * qr[j].w;
                }
            }
        }
    }

    // argmax over m per b (numpy first-occurrence tie-break). sidx overlays
    // Pl[0] (dead since the ft=15 barrier; final compute used Pl[1]).
    int* sidx = (int*)&Pl[0][0];
#pragma unroll
    for (int i = 0; i < 8; ++i) {
        float bv = acc[i][0];
        int   bi = tx;
#pragma unroll
        for (int j = 1; j < 8; ++j) {
            const float cv = acc[i][j];
            const int   ci = tx + 32 * j;
            if (cv > bv) { bv = cv; bi = ci; }
        }
#pragma unroll
        for (int off = 16; off >= 1; off >>= 1) {
            const float ov = __shfl_xor(bv, off);
            const int   oi = __shfl_xor(bi, off);
            if (ov > bv || (ov == bv && oi < bi)) { bv = ov; bi = oi; }
        }
        if (tx == 0) sidx[ty * 8 + i] = bi;
    }
    __syncthreads();

    // gather: out[b][l][:] = queue[l][sidx[b]][:]  (queue[l] is L2-hot)
    const int cb = t >> 6;     // 0..3
    const int cc = t & 63;     // float4 index within the 256-float row
#pragma unroll
    for (int b0 = 0; b0 < 64; b0 += 4) {
        const int b  = b0 + cb;
        const int mi = sidx[b];
        const float4 v = *reinterpret_cast<const float4*>(
            &queue[((size_t)l * M_ + mi) * F_ + cc * 4]);
        *reinterpret_cast<float4*>(&out[((size_t)b * L_ + l) * F_ + cc * 4]) = v;
    }
}

extern "C" void kernel_launch(void* const* d_in, const int* in_sizes, int n_in,
                              void* d_out, int out_size, void* d_ws, size_t ws_size,
                              hipStream_t stream) {
    const float* patch = (const float*)d_in[0];
    const float* queue = (const float*)d_in[1];
    float* out = (float*)d_out;
    mq_fused_kernel<<<dim3(L_), dim3(256), 0, stream>>>(patch, queue, out);
}

// Round 5
// 266.385 us; speedup vs baseline: 1.3653x; 1.0386x over previous
//
#include <hip/hip_runtime.h>

#define B_ 64
#define L_ 1024
#define M_ 256
#define F_ 256

// One block per l, 256 threads, rt 8x8: m = tx+32j, b = ty*8+i. K tiled by 32
// (128B row-chunks -> one HBM line fetch per line, no refetch). T14 staging:
// global->reg loads for tile ft+1 issued right after the barrier, in flight
// across the whole compute phase; reg->LDS write at next tile top.
// LDS = Q 32KB (XOR-swizzled) + P 8KB = 40960 B -> exactly 4 blocks/CU.
__launch_bounds__(256, 4)
__global__ void mq_fused_kernel(const float* __restrict__ patch,
                                const float* __restrict__ queue,
                                float* __restrict__ out) {
    const int l  = blockIdx.x;
    const int t  = threadIdx.x;
    const int tx = t & 31;
    const int ty = t >> 5;

    __shared__ __align__(16) float Ql[256 * 32];  // [row][slot], slot = chunk ^ (row&7)
    __shared__ __align__(16) float Pl[64 * 32];   // [row][chunk] linear

    const int lr = t >> 3;    // 0..31: staging row within 32-row group
    const int lc = t & 7;     // 0..7 : 16B chunk within a 128B row-slice

    // Q: thread stages rows r = lr + 32k (k=0..7), global chunk lc.
    // (lr+32k)&7 == lr&7 -> LDS slot lc^(lr&7) identical for all k.
    const float* qsrc = queue + ((size_t)l * M_ + lr) * F_ + lc * 4;
    const int    qslot = lc ^ (lr & 7);
    // P: thread stages rows lr and lr+32, chunk lc, linear slots.
    const float* psrc = patch + ((size_t)lr * L_ + l) * F_ + lc * 4;

    float4 sq[8], sp[2];
#pragma unroll
    for (int k = 0; k < 8; ++k)
        sq[k] = *reinterpret_cast<const float4*>(qsrc + (size_t)k * 32 * F_);
    sp[0] = *reinterpret_cast<const float4*>(psrc);
    sp[1] = *reinterpret_cast<const float4*>(psrc + (size_t)32 * L_ * F_);

    float acc[8][8];
#pragma unroll
    for (int i = 0; i < 8; ++i)
#pragma unroll
        for (int j = 0; j < 8; ++j) acc[i][j] = 0.f;

    for (int ft = 0; ft < 8; ++ft) {
        __syncthreads();     // previous tile's LDS reads complete
#pragma unroll
        for (int k = 0; k < 8; ++k)
            *reinterpret_cast<float4*>(&Ql[(lr + 32 * k) * 32 + qslot * 4]) = sq[k];
        *reinterpret_cast<float4*>(&Pl[lr * 32 + lc * 4])        = sp[0];
        *reinterpret_cast<float4*>(&Pl[(lr + 32) * 32 + lc * 4]) = sp[1];
        __syncthreads();     // writes visible

        // Issue next tile's global loads now -> in flight across compute.
        if (ft < 7) {
            const int o = (ft + 1) * 32;
#pragma unroll
            for (int k = 0; k < 8; ++k)
                sq[k] = *reinterpret_cast<const float4*>(qsrc + (size_t)k * 32 * F_ + o);
            sp[0] = *reinterpret_cast<const float4*>(psrc + o);
            sp[1] = *reinterpret_cast<const float4*>(psrc + (size_t)32 * L_ * F_ + o);
        }

#pragma unroll
        for (int f4 = 0; f4 < 8; ++f4) {
            const int qc = (f4 ^ (tx & 7)) * 4;    // (tx+32j)&7 == tx&7
            float4 qr[8];
#pragma unroll
            for (int j = 0; j < 8; ++j)
                qr[j] = *reinterpret_cast<const float4*>(
                    &Ql[(tx + 32 * j) * 32 + qc]);
#pragma unroll
            for (int i = 0; i < 8; ++i) {
                const float4 pv = *reinterpret_cast<const float4*>(
                    &Pl[(ty * 8 + i) * 32 + f4 * 4]);
#pragma unroll
                for (int j = 0; j < 8; ++j) {
                    acc[i][j] += pv.x * qr[j].x;
                    acc[i][j] += pv.y * qr[j].y;
                    acc[i][j] += pv.z * qr[j].z;
                    acc[i][j] += pv.w * qr[j].w;
                }
            }
        }
    }

    __syncthreads();   // all compute done before sidx overlays Pl

    // argmax over m per b (numpy first-occurrence tie-break).
    int* sidx = (int*)&Pl[0];
#pragma unroll
    for (int i = 0; i < 8; ++i) {
        float bv = acc[i][0];
        int   bi = tx;
#pragma unroll
        for (int j = 1; j < 8; ++j) {
            const float cv = acc[i][j];
            const int   ci = tx + 32 * j;
            if (cv > bv) { bv = cv; bi = ci; }
        }
#pragma unroll
        for (int off = 16; off >= 1; off >>= 1) {
            const float ov = __shfl_xor(bv, off);
            const int   oi = __shfl_xor(bi, off);
            if (ov > bv || (ov == bv && oi < bi)) { bv = ov; bi = oi; }
        }
        if (tx == 0) sidx[ty * 8 + i] = bi;
    }
    __syncthreads();

    // gather: out[b][l][:] = queue[l][sidx[b]][:]  (queue[l] is L2-hot)
    const int cb = t >> 6;     // 0..3
    const int cc = t & 63;     // float4 index within the 256-float row
#pragma unroll
    for (int b0 = 0; b0 < 64; b0 += 4) {
        const int b  = b0 + cb;
        const int mi = sidx[b];
        const float4 v = *reinterpret_cast<const float4*>(
            &queue[((size_t)l * M_ + mi) * F_ + cc * 4]);
        *reinterpret_cast<float4*>(&out[((size_t)b * L_ + l) * F_ + cc * 4]) = v;
    }
}

extern "C" void kernel_launch(void* const* d_in, const int* in_sizes, int n_in,
                              void* d_out, int out_size, void* d_ws, size_t ws_size,
                              hipStream_t stream) {
    const float* patch = (const float*)d_in[0];
    const float* queue = (const float*)d_in[1];
    float* out = (float*)d_out;
    mq_fused_kernel<<<dim3(L_), dim3(256), 0, stream>>>(patch, queue, out);
}

// Round 6
// 164.720 us; speedup vs baseline: 2.2080x; 1.6172x over previous
//
#include <hip/hip_runtime.h>

#define B_ 64
#define L_ 1024
#define M_ 256
#define F_ 256

typedef unsigned int u32;

// Async 16B global->LDS DMA. LDS dest = wave-uniform base (+lane*16 by HW);
// per-lane global source address carries the XOR swizzle (m173 pattern).
__device__ __forceinline__ void async_cp16(const float* g, float* l) {
    __builtin_amdgcn_global_load_lds(
        (const __attribute__((address_space(1))) u32*)g,
        (__attribute__((address_space(3))) u32*)l,
        16, 0, 0);
}

// One block per l, 256 threads, rt 8x8: m = tx+32j, b = ty*8+i. K tiled by 32
// (128B fetch granules). Q+P staged via global_load_lds, single-buffered:
// LDS = 32KB + 8KB = 40960 B -> exactly 4 blocks/CU (grid 1024 = 4/CU fully
// resident); per-tile load stall hidden by cross-block TLP.
// (256,2): VGPR cap 128 -- (256,4) empirically caps at 64 and spills (R4/R5).
__launch_bounds__(256, 2)
__global__ void mq_fused_kernel(const float* __restrict__ patch,
                                const float* __restrict__ queue,
                                float* __restrict__ out) {
    const int l  = blockIdx.x;
    const int t  = threadIdx.x;
    const int tx = t & 31;
    const int ty = t >> 5;

    __shared__ __align__(16) float Ql[256 * 32];  // [row][slot], slot = chunk^(row&7)
    __shared__ __align__(16) float Pl[64 * 32];   // [row][chunk] linear

    const int lane = t & 63;
    const int w    = t >> 6;          // wave 0..3
    const int lrow = lane >> 3;       // 0..7: row within an 8-row chunk
    const int lcol = lane & 7;        // 0..7: 16B chunk within a 128B row-slice

    // Q chunk g covers rows g*8..g*8+7; LDS linear dest lane order = row-major,
    // so lane (lrow,lcol) holds slot lcol of row g*8+lrow => source chunk
    // lcol ^ (row&7) = lcol ^ lrow (g*8 = 0 mod 8).
    const float* qsrc0 = queue + ((size_t)l * M_ + lrow) * F_ + (lcol ^ lrow) * 4;
    // P chunk g covers b-rows g*8..g*8+7, linear slots.
    const float* psrc0 = patch + ((size_t)lrow * L_ + l) * F_ + lcol * 4;

    float acc[8][8];
#pragma unroll
    for (int i = 0; i < 8; ++i)
#pragma unroll
        for (int j = 0; j < 8; ++j) acc[i][j] = 0.f;

    for (int ft = 0; ft < 8; ++ft) {
        __syncthreads();   // all reads of previous tile complete
        {
            const int o = ft * 32;
#pragma unroll
            for (int k = 0; k < 8; ++k) {
                const int g = w * 8 + k;
                async_cp16(qsrc0 + (size_t)g * 8 * F_ + o, &Ql[g * 256]);
            }
#pragma unroll
            for (int k = 0; k < 2; ++k) {
                const int g = w * 2 + k;
                async_cp16(psrc0 + (size_t)g * 8 * L_ * F_ + o, &Pl[g * 256]);
            }
        }
        __syncthreads();   // implicit vmcnt(0): DMA writes landed + visible

#pragma unroll
        for (int f4 = 0; f4 < 8; ++f4) {
            const int qc = (f4 ^ (tx & 7)) * 4;    // (tx+32j)&7 == tx&7
            float4 qr[8];
#pragma unroll
            for (int j = 0; j < 8; ++j)
                qr[j] = *reinterpret_cast<const float4*>(
                    &Ql[(tx + 32 * j) * 32 + qc]);
#pragma unroll
            for (int i = 0; i < 8; ++i) {
                const float4 pv = *reinterpret_cast<const float4*>(
                    &Pl[(ty * 8 + i) * 32 + f4 * 4]);
#pragma unroll
                for (int j = 0; j < 8; ++j) {
                    acc[i][j] += pv.x * qr[j].x;
                    acc[i][j] += pv.y * qr[j].y;
                    acc[i][j] += pv.z * qr[j].z;
                    acc[i][j] += pv.w * qr[j].w;
                }
            }
        }
    }

    __syncthreads();   // last tile's P reads done before sidx overlays Pl

    // argmax over m per b (numpy first-occurrence tie-break).
    int* sidx = (int*)&Pl[0];
#pragma unroll
    for (int i = 0; i < 8; ++i) {
        float bv = acc[i][0];
        int   bi = tx;
#pragma unroll
        for (int j = 1; j < 8; ++j) {
            const float cv = acc[i][j];
            const int   ci = tx + 32 * j;
            if (cv > bv) { bv = cv; bi = ci; }
        }
#pragma unroll
        for (int off = 16; off >= 1; off >>= 1) {
            const float ov = __shfl_xor(bv, off);
            const int   oi = __shfl_xor(bi, off);
            if (ov > bv || (ov == bv && oi < bi)) { bv = ov; bi = oi; }
        }
        if (tx == 0) sidx[ty * 8 + i] = bi;
    }
    __syncthreads();

    // gather: out[b][l][:] = queue[l][sidx[b]][:]  (queue[l] is L2-hot)
    const int cb = t >> 6;     // 0..3
    const int cc = t & 63;     // float4 index within the 256-float row
#pragma unroll
    for (int b0 = 0; b0 < 64; b0 += 4) {
        const int b  = b0 + cb;
        const int mi = sidx[b];
        const float4 v = *reinterpret_cast<const float4*>(
            &queue[((size_t)l * M_ + mi) * F_ + cc * 4]);
        *reinterpret_cast<float4*>(&out[((size_t)b * L_ + l) * F_ + cc * 4]) = v;
    }
}

extern "C" void kernel_launch(void* const* d_in, const int* in_sizes, int n_in,
                              void* d_out, int out_size, void* d_ws, size_t ws_size,
                              hipStream_t stream) {
    const float* patch = (const float*)d_in[0];
    const float* queue = (const float*)d_in[1];
    float* out = (float*)d_out;
    mq_fused_kernel<<<dim3(L_), dim3(256), 0, stream>>>(patch, queue, out);
}

// Round 7
// 150.037 us; speedup vs baseline: 2.4241x; 1.0979x over previous
//
#include <hip/hip_runtime.h>

#define B_ 64
#define L_ 1024
#define M_ 256
#define F_ 256

typedef __attribute__((ext_vector_type(8))) short short8;   // bf16x8 frag (4 VGPR)
typedef __attribute__((ext_vector_type(4))) float f32x4;    // MFMA C/D
typedef unsigned int u32;

struct Frag3 { short8 h, m, l; };

__device__ __forceinline__ u32 asu(float f) { union { float f; u32 u; } c; c.f = f; return c.u; }
__device__ __forceinline__ float asf(u32 u) { union { float f; u32 u; } c; c.u = u; return c.f; }

// Pack hi16(lo-elem) into low half, hi16(hi-elem) into high half. Even if the
// operand order is backwards it only swaps k-pairs identically on A and B,
// which cancels in the contraction.
__device__ __forceinline__ u32 pack2(u32 lo, u32 hi) {
    return __builtin_amdgcn_perm(hi, lo, 0x07060302u);
}

// Exact 3-way bf16 truncation split of 8 fp32: x = h + m + l + O(2^-32 x).
__device__ __forceinline__ Frag3 split8(float4 a, float4 b) {
    float x[8] = {a.x, a.y, a.z, a.w, b.x, b.y, b.z, b.w};
    u32 xb[8], rb[8], sb[8];
#pragma unroll
    for (int e = 0; e < 8; ++e) {
        xb[e] = asu(x[e]);
        float hf = asf(xb[e] & 0xFFFF0000u);
        float r  = x[e] - hf;                 // exact (shared exponent)
        rb[e] = asu(r);
        float mf = asf(rb[e] & 0xFFFF0000u);
        float r2 = r - mf;                    // exact
        sb[e] = asu(r2);
    }
    union { u32 w[4]; short8 s; } H, M, Lo;
#pragma unroll
    for (int d = 0; d < 4; ++d) {
        H.w[d]  = pack2(xb[2 * d], xb[2 * d + 1]);
        M.w[d]  = pack2(rb[2 * d], rb[2 * d + 1]);
        Lo.w[d] = pack2(sb[2 * d], sb[2 * d + 1]);
    }
    Frag3 f; f.h = H.s; f.m = M.s; f.l = Lo.s; return f;
}

// One block per l, 256 threads = 4 waves. Wave w owns b-tile w (rows w*16..+15)
// x all 16 m-tiles. MFMA 16x16x32 bf16, 6 split-products per (mt, k-step),
// fragments loaded directly from global (no LDS, no main-loop barriers).
// A-frag: lane: row = lane&15, f-cols = 8*(lane>>4) + kk*32 (16x128B segs).
// D: col(m) = lane&15, row(b) = 4*(lane>>4) + reg   [verified m89].
__launch_bounds__(256, 2)
__global__ void mq_mfma_kernel(const float* __restrict__ patch,
                               const float* __restrict__ queue,
                               float* __restrict__ out) {
    const int l    = blockIdx.x;
    const int t    = threadIdx.x;
    const int lane = t & 63;
    const int w    = t >> 6;        // wave = b-tile index 0..3
    const int r16  = lane & 15;     // A-row / B-col within tile
    const int kg   = lane >> 4;     // k-group 0..3 (f-offset 8*kg)

    __shared__ int sidx[64];

    f32x4 acc[16];
#pragma unroll
    for (int mt = 0; mt < 16; ++mt) acc[mt] = (f32x4)0.f;

    const float* Abase = patch + ((size_t)(w * 16 + r16) * L_ + l) * F_ + kg * 8;
    const float* Bbase = queue + ((size_t)l * M_ + r16) * F_ + kg * 8;

#pragma unroll 1
    for (int kk = 0; kk < 8; ++kk) {
        const float* ap = Abase + kk * 32;
        const Frag3 A = split8(*reinterpret_cast<const float4*>(ap),
                               *reinterpret_cast<const float4*>(ap + 4));
        const float* bp0 = Bbase + kk * 32;
        // one-deep manual pipeline on the B loads
        float4 nb0 = *reinterpret_cast<const float4*>(bp0);
        float4 nb1 = *reinterpret_cast<const float4*>(bp0 + 4);
#pragma unroll
        for (int mt = 0; mt < 16; ++mt) {
            const float4 cb0 = nb0, cb1 = nb1;
            if (mt < 15) {
                const float* bp = bp0 + (size_t)(mt + 1) * 16 * F_;
                nb0 = *reinterpret_cast<const float4*>(bp);
                nb1 = *reinterpret_cast<const float4*>(bp + 4);
            }
            const Frag3 Bf = split8(cb0, cb1);
            // small terms first for accumulation accuracy
            acc[mt] = __builtin_amdgcn_mfma_f32_16x16x32_bf16(A.m, Bf.m, acc[mt], 0, 0, 0);
            acc[mt] = __builtin_amdgcn_mfma_f32_16x16x32_bf16(A.h, Bf.l, acc[mt], 0, 0, 0);
            acc[mt] = __builtin_amdgcn_mfma_f32_16x16x32_bf16(A.l, Bf.h, acc[mt], 0, 0, 0);
            acc[mt] = __builtin_amdgcn_mfma_f32_16x16x32_bf16(A.h, Bf.m, acc[mt], 0, 0, 0);
            acc[mt] = __builtin_amdgcn_mfma_f32_16x16x32_bf16(A.m, Bf.h, acc[mt], 0, 0, 0);
            acc[mt] = __builtin_amdgcn_mfma_f32_16x16x32_bf16(A.h, Bf.h, acc[mt], 0, 0, 0);
        }
    }

    // argmax over m per b-row (numpy first-occurrence). Lane holds rows
    // b = w*16 + 4*kg + r (r=0..3), col m = mt*16 + r16. In-lane mt ascending
    // with strict '>' keeps lowest m; 16-lane butterfly prefers lower idx on tie.
#pragma unroll
    for (int r = 0; r < 4; ++r) {
        float bv = acc[0][r];
        int   bi = r16;
#pragma unroll
        for (int mt = 1; mt < 16; ++mt) {
            const float cv = acc[mt][r];
            const int   ci = mt * 16 + r16;
            if (cv > bv) { bv = cv; bi = ci; }
        }
#pragma unroll
        for (int off = 8; off >= 1; off >>= 1) {
            const float ov = __shfl_xor(bv, off);
            const int   oi = __shfl_xor(bi, off);
            if (ov > bv || (ov == bv && oi < bi)) { bv = ov; bi = oi; }
        }
        if (r16 == 0) sidx[w * 16 + 4 * kg + r] = bi;
    }
    __syncthreads();

    // gather: out[b][l][:] = queue[l][sidx[b]][:]  (queue[l] is L2-hot)
    const int cb = t >> 6;     // 0..3
    const int cc = t & 63;     // float4 index within the 256-float row
#pragma unroll
    for (int b0 = 0; b0 < 64; b0 += 4) {
        const int b  = b0 + cb;
        const int mi = sidx[b];
        const float4 v = *reinterpret_cast<const float4*>(
            &queue[((size_t)l * M_ + mi) * F_ + cc * 4]);
        *reinterpret_cast<float4*>(&out[((size_t)b * L_ + l) * F_ + cc * 4]) = v;
    }
}

extern "C" void kernel_launch(void* const* d_in, const int* in_sizes, int n_in,
                              void* d_out, int out_size, void* d_ws, size_t ws_size,
                              hipStream_t stream) {
    const float* patch = (const float*)d_in[0];
    const float* queue = (const float*)d_in[1];
    float* out = (float*)d_out;
    mq_mfma_kernel<<<dim3(L_), dim3(256), 0, stream>>>(patch, queue, out);
}

// Round 8
// 130.177 us; speedup vs baseline: 2.7939x; 1.1526x over previous
//
#include <hip/hip_runtime.h>

#define B_ 64
#define L_ 1024
#define M_ 256
#define F_ 256

typedef __attribute__((ext_vector_type(8))) short short8;    // 8 bf16 (4 VGPR)
typedef __attribute__((ext_vector_type(16))) float f32x16;   // 32x32 MFMA C/D
typedef unsigned int u32;

struct Frag3 { short8 h, m, l; };

__device__ __forceinline__ u32 asu(float f) { union { float f; u32 u; } c; c.f = f; return c.u; }
__device__ __forceinline__ float asf(u32 u) { union { float f; u32 u; } c; c.u = u; return c.f; }
__device__ __forceinline__ u32 pack2(u32 lo, u32 hi) {
    return __builtin_amdgcn_perm(hi, lo, 0x07060302u);
}

// Exact 3-way bf16 truncation split of 8 fp32: x = h + m + l (top 24 mantissa bits).
__device__ __forceinline__ Frag3 split8(float4 a, float4 b) {
    float x[8] = {a.x, a.y, a.z, a.w, b.x, b.y, b.z, b.w};
    u32 xb[8], rb[8], sb[8];
#pragma unroll
    for (int e = 0; e < 8; ++e) {
        xb[e] = asu(x[e]);
        float hf = asf(xb[e] & 0xFFFF0000u);
        float r  = x[e] - hf;                 // exact
        rb[e] = asu(r);
        float mf = asf(rb[e] & 0xFFFF0000u);
        float r2 = r - mf;                    // exact
        sb[e] = asu(r2);
    }
    union { u32 w[4]; short8 s; } H, M, Lo;
#pragma unroll
    for (int d = 0; d < 4; ++d) {
        H.w[d]  = pack2(xb[2 * d], xb[2 * d + 1]);
        M.w[d]  = pack2(rb[2 * d], rb[2 * d + 1]);
        Lo.w[d] = pack2(sb[2 * d], sb[2 * d + 1]);
    }
    Frag3 f; f.h = H.s; f.m = M.s; f.l = Lo.s; return f;
}

#define MFMA6(ACC, A, Bf)                                                        \
    ACC = __builtin_amdgcn_mfma_f32_32x32x16_bf16((A).m, (Bf).m, ACC, 0, 0, 0);  \
    ACC = __builtin_amdgcn_mfma_f32_32x32x16_bf16((A).h, (Bf).l, ACC, 0, 0, 0);  \
    ACC = __builtin_amdgcn_mfma_f32_32x32x16_bf16((A).l, (Bf).h, ACC, 0, 0, 0);  \
    ACC = __builtin_amdgcn_mfma_f32_32x32x16_bf16((A).h, (Bf).m, ACC, 0, 0, 0);  \
    ACC = __builtin_amdgcn_mfma_f32_32x32x16_bf16((A).m, (Bf).h, ACC, 0, 0, 0);  \
    ACC = __builtin_amdgcn_mfma_f32_32x32x16_bf16((A).h, (Bf).h, ACC, 0, 0, 0)

// One block per l, 256 threads = 4 waves. Wave (bt=w&1, mtg=w>>1):
// b-rows bt*32..+31, m-cols mtg*128..+127 (4 m-tiles of 32).
// 32x32x16 MFMA: A lane = patch row (lane&31), k-half lane>>5 (8 f each);
// B lane = queue row; D: col(m)=lane&31, row=(reg&3)+8*(reg>>2)+4*(lane>>5).
__launch_bounds__(256, 2)
__global__ void mq_mfma32_kernel(const float* __restrict__ patch,
                                 const float* __restrict__ queue,
                                 float* __restrict__ out) {
    const int l    = blockIdx.x;
    const int t    = threadIdx.x;
    const int lane = t & 63;
    const int w    = t >> 6;
    const int bt   = w & 1;
    const int mtg  = w >> 1;
    const int r32  = lane & 31;
    const int kh   = lane >> 5;     // k-half: f-offset kh*8

    __shared__ float pval[2][64];
    __shared__ int   pidx[2][64];
    __shared__ int   sidx[64];

    f32x16 acc[4];
#pragma unroll
    for (int mt = 0; mt < 4; ++mt) acc[mt] = (f32x16)0.f;

    const float* Abase = patch + ((size_t)(bt * 32 + r32) * L_ + l) * F_ + kh * 8;
    const float* Bbase = queue + ((size_t)l * M_ + mtg * 128 + r32) * F_ + kh * 8;

#pragma unroll 1
    for (int kk = 0; kk < 16; ++kk) {
        const float* ap = Abase + kk * 16;
        const float* bp = Bbase + kk * 16;
        // Issue A + first half of B loads, then stagger the rest to cap VGPR.
        const float4 a0  = *reinterpret_cast<const float4*>(ap);
        const float4 a1  = *reinterpret_cast<const float4*>(ap + 4);
        const float4 b00 = *reinterpret_cast<const float4*>(bp);
        const float4 b01 = *reinterpret_cast<const float4*>(bp + 4);
        const float4 b10 = *reinterpret_cast<const float4*>(bp + (size_t)32 * F_);
        const float4 b11 = *reinterpret_cast<const float4*>(bp + (size_t)32 * F_ + 4);
        const Frag3 A  = split8(a0, a1);
        const float4 b20 = *reinterpret_cast<const float4*>(bp + (size_t)64 * F_);
        const float4 b21 = *reinterpret_cast<const float4*>(bp + (size_t)64 * F_ + 4);
        const float4 b30 = *reinterpret_cast<const float4*>(bp + (size_t)96 * F_);
        const float4 b31 = *reinterpret_cast<const float4*>(bp + (size_t)96 * F_ + 4);
        const Frag3 B0 = split8(b00, b01);
        MFMA6(acc[0], A, B0);
        const Frag3 B1 = split8(b10, b11);
        MFMA6(acc[1], A, B1);
        const Frag3 B2 = split8(b20, b21);
        MFMA6(acc[2], A, B2);
        const Frag3 B3 = split8(b30, b31);
        MFMA6(acc[3], A, B3);
    }

    // Per-wave argmax over its 128 m-cols for each of its 32 b-rows.
    // In-lane mt ascending (m ascending) + strict '>' keeps lowest m;
    // 32-lane butterfly prefers lower idx on tie (numpy first-occurrence).
#pragma unroll
    for (int r = 0; r < 16; ++r) {
        float bv = acc[0][r];
        int   bi = mtg * 128 + r32;
#pragma unroll
        for (int mt = 1; mt < 4; ++mt) {
            const float cv = acc[mt][r];
            const int   ci = mtg * 128 + mt * 32 + r32;
            if (cv > bv) { bv = cv; bi = ci; }
        }
#pragma unroll
        for (int off = 16; off >= 1; off >>= 1) {
            const float ov = __shfl_xor(bv, off);
            const int   oi = __shfl_xor(bi, off);
            if (ov > bv || (ov == bv && oi < bi)) { bv = ov; bi = oi; }
        }
        if (r32 == 0) {
            const int b = bt * 32 + (r & 3) + 8 * (r >> 2) + 4 * kh;
            pval[mtg][b] = bv;
            pidx[mtg][b] = bi;
        }
    }
    __syncthreads();

    // Combine the two m-halves; mtg0 (lower m) wins ties -> first occurrence.
    if (t < 64) {
        const float v0 = pval[0][t], v1 = pval[1][t];
        sidx[t] = (v1 > v0) ? pidx[1][t] : pidx[0][t];
    }
    __syncthreads();

    // gather: out[b][l][:] = queue[l][sidx[b]][:]  (queue[l] is L2-hot)
    const int cb = t >> 6;     // 0..3
    const int cc = t & 63;     // float4 index within the 256-float row
#pragma unroll
    for (int b0 = 0; b0 < 64; b0 += 4) {
        const int b  = b0 + cb;
        const int mi = sidx[b];
        const float4 v = *reinterpret_cast<const float4*>(
            &queue[((size_t)l * M_ + mi) * F_ + cc * 4]);
        *reinterpret_cast<float4*>(&out[((size_t)b * L_ + l) * F_ + cc * 4]) = v;
    }
}

extern "C" void kernel_launch(void* const* d_in, const int* in_sizes, int n_in,
                              void* d_out, int out_size, void* d_ws, size_t ws_size,
                              hipStream_t stream) {
    const float* patch = (const float*)d_in[0];
    const float* queue = (const float*)d_in[1];
    float* out = (float*)d_out;
    mq_mfma32_kernel<<<dim3(L_), dim3(256), 0, stream>>>(patch, queue, out);
}